// Round 2
// baseline (301.792 us; speedup 1.0000x reference)
//
#include <hip/hip_runtime.h>

#define N_NODES 100000
#define N_EDGES 1600000
#define IN_DIM 128
#define OUT_DIM 32
#define SCAN_BLK 256
#define N_SCAN_BLKS ((N_NODES + SCAN_BLK - 1) / SCAN_BLK)   // 391

// -------- kernel 1: support = X @ W  (fp32, memory-bound) --------
__global__ __launch_bounds__(256) void gemm_support(
    const float* __restrict__ x, const float* __restrict__ w,
    float* __restrict__ support) {
  __shared__ float ws[IN_DIM][OUT_DIM];   // 16 KB
  __shared__ float xs[8][IN_DIM];         // 4 KB
  const int tid = threadIdx.x;

  for (int i = tid; i < IN_DIM * OUT_DIM; i += 256)
    ws[i / OUT_DIM][i % OUT_DIM] = w[i];

  const int row0 = blockIdx.x * 8;
  for (int i = tid; i < 8 * IN_DIM; i += 256) {
    const int r = i / IN_DIM, k = i % IN_DIM;
    const int row = row0 + r;
    xs[r][k] = (row < N_NODES) ? x[(long long)row * IN_DIM + k] : 0.f;
  }
  __syncthreads();

  const int r = tid >> 5;
  const int c = tid & 31;
  const int row = row0 + r;
  if (row >= N_NODES) return;

  float acc = 0.f;
#pragma unroll
  for (int k = 0; k < IN_DIM; ++k)
    acc = fmaf(xs[r][k], ws[k][c], acc);
  support[(long long)row * OUT_DIM + c] = acc;
}

// -------- CSR build: histogram --------
__global__ __launch_bounds__(256) void hist_rows(
    const int* __restrict__ rows, int* __restrict__ counts) {
  const int e = blockIdx.x * 256 + threadIdx.x;
  if (e < N_EDGES) atomicAdd(&counts[rows[e]], 1);
}

// -------- CSR build: scan stage 1 (per-block exclusive scan + block sums) ----
__global__ __launch_bounds__(SCAN_BLK) void scan1(
    const int* __restrict__ counts, int* __restrict__ offsets,
    int* __restrict__ bsum) {
  __shared__ int sm[SCAN_BLK];
  const int t = threadIdx.x;
  const int i = blockIdx.x * SCAN_BLK + t;
  const int c = (i < N_NODES) ? counts[i] : 0;
  sm[t] = c;
  __syncthreads();
  for (int off = 1; off < SCAN_BLK; off <<= 1) {
    int v = (t >= off) ? sm[t - off] : 0;
    __syncthreads();
    sm[t] += v;
    __syncthreads();
  }
  if (i < N_NODES) offsets[i] = sm[t] - c;   // exclusive within block
  if (t == SCAN_BLK - 1) bsum[blockIdx.x] = sm[t];
}

// -------- CSR build: scan stage 2 (scan of 391 block sums, one block) -------
__global__ __launch_bounds__(512) void scan2(
    const int* __restrict__ bsum, int* __restrict__ bscan) {
  __shared__ int sm[512];
  const int t = threadIdx.x;
  sm[t] = (t < N_SCAN_BLKS) ? bsum[t] : 0;
  __syncthreads();
  for (int off = 1; off < 512; off <<= 1) {
    int v = (t >= off) ? sm[t - off] : 0;
    __syncthreads();
    sm[t] += v;
    __syncthreads();
  }
  const int ex = (t == 0) ? 0 : sm[t - 1];
  if (t < N_SCAN_BLKS) bscan[t] = ex;
}

// -------- CSR build: scan stage 3 (add block offset; init cursor) -----------
__global__ __launch_bounds__(SCAN_BLK) void scan3(
    int* __restrict__ offsets, const int* __restrict__ bscan,
    int* __restrict__ cursor) {
  const int t = threadIdx.x;
  const int i = blockIdx.x * SCAN_BLK + t;
  if (i < N_NODES) {
    const int v = offsets[i] + bscan[blockIdx.x];
    offsets[i] = v;
    cursor[i] = v;
  }
  if (i == 0) offsets[N_NODES] = N_EDGES;
}

// -------- CSR build: scatter edges into (col,val) slots ----------------------
__global__ __launch_bounds__(256) void scatter_to_csr(
    const int* __restrict__ rows, const int* __restrict__ cols,
    const float* __restrict__ vals, int* __restrict__ cursor,
    int2* __restrict__ cv) {
  const int e = blockIdx.x * 256 + threadIdx.x;
  if (e >= N_EDGES) return;
  const int r = rows[e];
  const int p = atomicAdd(&cursor[r], 1);
  cv[p] = make_int2(cols[e], __float_as_int(vals[e]));
}

// -------- SpMM over CSR: half-wave per row, lane = output dim ---------------
__global__ __launch_bounds__(256) void spmm_csr(
    const int* __restrict__ off, const int2* __restrict__ cv,
    const float* __restrict__ support, const float* __restrict__ bias,
    float* __restrict__ out) {
  const int tid = threadIdx.x;
  const int lane = tid & 31;          // output dim
  const int sub = tid >> 5;           // 0..7
  const int row = blockIdx.x * 8 + sub;
  if (row >= N_NODES) return;
  const int s = off[row];
  const int e = off[row + 1];

  float acc0 = 0.f, acc1 = 0.f;
  int i = s;
  for (; i + 1 < e; i += 2) {
    const int2 p0 = cv[i];
    const int2 p1 = cv[i + 1];
    acc0 = fmaf(__int_as_float(p0.y),
                support[(long long)p0.x * OUT_DIM + lane], acc0);
    acc1 = fmaf(__int_as_float(p1.y),
                support[(long long)p1.x * OUT_DIM + lane], acc1);
  }
  if (i < e) {
    const int2 p = cv[i];
    acc0 = fmaf(__int_as_float(p.y),
                support[(long long)p.x * OUT_DIM + lane], acc0);
  }
  out[(long long)row * OUT_DIM + lane] = acc0 + acc1 + bias[lane];
}

extern "C" void kernel_launch(void* const* d_in, const int* in_sizes, int n_in,
                              void* d_out, int out_size, void* d_ws, size_t ws_size,
                              hipStream_t stream) {
  const float* x        = (const float*)d_in[0];
  const int*   adj_rows = (const int*)d_in[1];
  const int*   adj_cols = (const int*)d_in[2];
  const float* adj_vals = (const float*)d_in[3];
  const float* weight   = (const float*)d_in[4];
  const float* bias     = (const float*)d_in[5];
  float* out = (float*)d_out;

  // ---- workspace layout (≈ 26.8 MB) ----
  char* w = (char*)d_ws;
  float* support = (float*)w;                       // 12,800,000 B
  int*   counts  = (int*)(w + 12800000);            // (N+32)*4 = 400,128 B
  int*   offsets = counts + (N_NODES + 32);         // 400,128 B
  int*   cursor  = offsets + (N_NODES + 32);        // 400,128 B
  int*   bsum    = cursor + (N_NODES + 32);         // 512*4
  int*   bscan   = bsum + 512;                      // 512*4
  int2*  cv      = (int2*)(bscan + 512);            // 12,800,000 B

  hipMemsetAsync(counts, 0, (size_t)N_NODES * sizeof(int), stream);

  gemm_support<<<(N_NODES + 7) / 8, 256, 0, stream>>>(x, weight, support);

  hist_rows<<<(N_EDGES + 255) / 256, 256, 0, stream>>>(adj_rows, counts);
  scan1<<<N_SCAN_BLKS, SCAN_BLK, 0, stream>>>(counts, offsets, bsum);
  scan2<<<1, 512, 0, stream>>>(bsum, bscan);
  scan3<<<N_SCAN_BLKS, SCAN_BLK, 0, stream>>>(offsets, bscan, cursor);
  scatter_to_csr<<<(N_EDGES + 255) / 256, 256, 0, stream>>>(
      adj_rows, adj_cols, adj_vals, cursor, cv);

  spmm_csr<<<(N_NODES + 7) / 8, 256, 0, stream>>>(offsets, cv, support, bias,
                                                  out);
}